// Round 1
// 5196.754 us; speedup vs baseline: 3.5311x; 3.5311x over previous
//
#include <hip/hip_runtime.h>
#include <hip/hip_bf16.h>

// Problem constants
#define T_ 512
#define B_ 256
#define I_ 128
#define H_ 256
#define NB_ 16   // batch groups (16 rows each) -- independent serial chains
#define NC_ 16   // column-slice WGs per group (16 h-cols each)
#define PL_ 65536  // one h plane (B*H) in bf16 elems

typedef unsigned short ushort_t;
typedef __attribute__((ext_vector_type(8))) short short8;  // 8 bf16 (4 VGPRs)
typedef __attribute__((ext_vector_type(4))) float f32x4;

// d_ws layout (ushort units): h stored as 3 bf16 planes (hi/mid/lo = fp32-equivalent)
// h0: [2 bufs][3 planes][B*H]  -> offset buf*3*PL_ + plane*PL_
#define OFF_H0 0
#define OFF_H1 (6 * PL_)           // 393216
#define WS_USHORTS (12 * PL_)      // 786432; flags (int) at byte offset WS_USHORTS*2
// flags[0..511]   : f0 per group (stride 32)
// flags[512..1023]: f1 per group (stride 32)
// flags[1024..1279]: per-WG xcd id (g*16+cs)
// flags[1280..1791]: per-group arrival counters (stride 32)
#define N_FLAGS 1792

__device__ __forceinline__ ushort_t f2bf(float f) {  // RNE f32->bf16
  unsigned int u = __float_as_uint(f);
  u += 0x7fffu + ((u >> 16) & 1u);
  return (ushort_t)(u >> 16);
}
__device__ __forceinline__ float bf2f(ushort_t u) {
  return __uint_as_float(((unsigned int)u) << 16);
}

// ---------------- prep: state 3-plane split + flag zeroing ----------------
__global__ void prep_kernel(const float* __restrict__ state, ushort_t* __restrict__ ws,
                            int* __restrict__ flags) {
  int i = blockIdx.x * 256 + threadIdx.x;
  if (i < 131072) {
    int tsr = i >> 16, j = i & 65535;
    float f = state[i];
    ushort_t a = f2bf(f); f -= bf2f(a);
    ushort_t b = f2bf(f); f -= bf2f(b);
    ushort_t c = f2bf(f);
    ushort_t* base = ws + (tsr ? OFF_H1 : OFF_H0) + 3 * PL_;  // init -> buf1
    base[j] = a; base[PL_ + j] = b; base[2 * PL_ + j] = c;
  } else if (i < 131072 + N_FLAGS) {
    flags[i - 131072] = 0;
  }
}

// ---------------- fragment helpers (verified gfx950 16x16x32 layouts) ----------------
// A/B frag: element j of lane l maps to [m|n = l&15][k = (l>>4)*8 + j]
struct frag3 { short8 h, m, l; };

// split fp32 (16B-aligned, 8 consecutive) into 3 bf16 fragments (24 mantissa bits ~ fp32)
__device__ __forceinline__ frag3 split3(const float* p) {
  f32x4 a = *(const f32x4*)p;
  f32x4 b = *(const f32x4*)(p + 4);
  float v[8] = {a[0], a[1], a[2], a[3], b[0], b[1], b[2], b[3]};
  frag3 r;
#pragma unroll
  for (int j = 0; j < 8; j++) {
    float f = v[j];
    ushort_t x = f2bf(f); f -= bf2f(x);
    ushort_t y = f2bf(f); f -= bf2f(y);
    ushort_t z = f2bf(f);
    r.h[j] = (short)x; r.m[j] = (short)y; r.l[j] = (short)z;
  }
  return r;
}
// weight B-frag (rows of W are output cols n): W[row + n][kc*32 + quad*8 + j]
__device__ __forceinline__ frag3 ldw3(const float* base, int ldk, int row, int kc, int lane) {
  return split3(base + (size_t)(row + (lane & 15)) * ldk + kc * 32 + ((lane >> 4) << 3));
}
// x A-frag from fp32
__device__ __forceinline__ frag3 lda_x3(const float* base, int ldk, int kc, int lane) {
  return split3(base + (size_t)(lane & 15) * ldk + kc * 32 + ((lane >> 4) << 3));
}
// sc0 load: bypass per-CU L1, probe the XCD-shared L2 (intra-XCD coherent point).
// In slow (cross-XCD) path the acquire __threadfence has invalidated L2, so sc0
// misses to the coherence point -> also correct.
__device__ __forceinline__ short8 ldg_sc0(const ushort_t* p) {
  short8 v;
  asm volatile("global_load_dwordx4 %0, %1, off sc0"
               : "=v"(v)
               : "v"(p)
               : "memory");
  return v;
}
// one h plane A-frag
__device__ __forceinline__ short8 lda_plane(const ushort_t* plane, int gb, int kc, int lane) {
  const ushort_t* p = plane + ((size_t)gb + (lane & 15)) * H_ + kc * 32 + ((lane >> 4) << 3);
  return ldg_sc0(p);
}
__device__ __forceinline__ frag3 lda_h3(const ushort_t* bufbase, int gb, int kc, int lane) {
  frag3 r;
  r.h = lda_plane(bufbase,           gb, kc, lane);
  r.m = lda_plane(bufbase + PL_,     gb, kc, lane);
  r.l = lda_plane(bufbase + 2 * PL_, gb, kc, lane);
  return r;
}
// wait for asm loads; sched_barrier keeps MFMAs from hoisting past the waitcnt (rule #18)
#define WAITVM() do { \
  asm volatile("s_waitcnt vmcnt(0)" ::: "memory"); \
  __builtin_amdgcn_sched_barrier(0); \
} while (0)

__device__ __forceinline__ f32x4 mfma_(short8 a, short8 b, f32x4 c) {
  return __builtin_amdgcn_mfma_f32_16x16x32_bf16(a, b, c, 0, 0, 0);
}
// split-precision product: all terms >= 2^-24 relative kept (fp32-equivalent)
__device__ __forceinline__ f32x4 macc(const frag3& A, const frag3& B, f32x4 c) {
  c = mfma_(A.h, B.h, c);
  c = mfma_(A.m, B.h, c);
  c = mfma_(A.h, B.m, c);
  c = mfma_(A.l, B.h, c);
  c = mfma_(A.h, B.l, c);
  c = mfma_(A.m, B.m, c);
  return c;
}
// D frag: reg r of lane l -> row (l>>4)*4+r, col l&15 ; slot stride padded to 17
__device__ __forceinline__ void store_d(float* s, f32x4 d, int lane) {
  int c = lane & 15, q = lane >> 4;
  float* p = s + (q * 4) * 17 + c;
#pragma unroll
  for (int r = 0; r < 4; r++) p[r * 17] = d[r];
}
// RELAXED spin (no per-poll cache invalidate!); caller decides fence policy after success.
// Bounded to avoid harness hang (sticky abort -> everything free-runs after).
__device__ __forceinline__ int spinwait(int* p, int tgt, int aborted) {
  if (aborted || tgt <= 0) return aborted;
  int n = 0;
  while (__hip_atomic_load(p, __ATOMIC_RELAXED, __HIP_MEMORY_SCOPE_AGENT) < tgt) {
    if (++n > (1 << 20)) return 1;
  }
  return 0;
}
__device__ __forceinline__ int get_xcc() {
  int x;
  asm volatile("s_getreg_b32 %0, hwreg(HW_REG_XCC_ID)" : "=s"(x));
  return x & 15;
}

// ---------------- persistent recurrence kernel (plain launch, 256 blocks = 1/CU) ----------------
__global__ void __launch_bounds__(256, 1)
gru_main(const float* __restrict__ x,
         const float* __restrict__ Wi0, const float* __restrict__ Wh0, const float* __restrict__ Wn0,
         const float* __restrict__ Wi1, const float* __restrict__ Wh1, const float* __restrict__ Wn1,
         const float* __restrict__ state, float* __restrict__ out,
         ushort_t* __restrict__ ws, int* __restrict__ flags) {
  __shared__ float sP[8][16][17];  // MFMA partial-sum slots
  __shared__ float h0own[256];     // this WG's fp32 h-slice carry
  __shared__ float h1own[256];
  __shared__ int s_fast;

  const int tid = (int)threadIdx.x;
  const int lane = tid & 63;
  const int w = tid >> 6;                 // wave id 0..3
  const int g = (int)blockIdx.x & 15;     // batch group
  const int cs = (int)blockIdx.x >> 4;    // column slice
  const int gb = g * 16;                  // batch row base
  const int cb = cs * 16;                 // h-col base

  ushort_t* h0sh = ws + OFF_H0;
  ushort_t* h1sh = ws + OFF_H1;
  int* f0 = flags + g * 32;
  int* f1 = flags + (NB_ + g) * 32;
  int* xarr = flags + 1024;               // per-WG xcd ids
  int* actr = flags + 1280 + g * 32;      // per-group arrival counter

  const int pm = tid >> 4;  // pointwise row (batch)
  const int pc = tid & 15;  // pointwise col

  h0own[tid] = state[(size_t)(gb + pm) * H_ + cb + pc];
  h1own[tid] = state[(size_t)B_ * H_ + (size_t)(gb + pm) * H_ + cb + pc];

  // ---- one-time group XCD-locality check: all 16 col-slice WGs on one XCD? ----
  if (tid == 0) {
    int myx = get_xcc();
    __hip_atomic_store(&xarr[g * 16 + cs], myx, __ATOMIC_RELAXED, __HIP_MEMORY_SCOPE_AGENT);
    __threadfence();
    __hip_atomic_fetch_add(actr, 1, __ATOMIC_RELEASE, __HIP_MEMORY_SCOPE_AGENT);
    int ab = spinwait(actr, NC_, 0);
    __threadfence();
    int f = ab ? 0 : 1;
    if (!ab) {
#pragma unroll
      for (int i = 0; i < NC_; i++)
        f &= (__hip_atomic_load(&xarr[g * 16 + i], __ATOMIC_RELAXED,
                                __HIP_MEMORY_SCOPE_AGENT) == myx);
    }
    s_fast = f;
  }

  // Stationary weight B-fragments in registers (3-way split).
  // L0: w0: g_r x-part(F0-3)+h k0-3(F4-7); w1: g_r h k4-7(F0-3)+npre(F4-7);
  //     w2: g_z x-part+h k0-3;             w3: g_z h k4-7(F0-3)
  // L1: w0: g_r Q-side; w1: g_r R-side; w2: g_z Q-side; w3: g_z R-side; n1 2 chunks each (G8,G9)
  frag3 F3[8], G3[10];
  if (w == 0) {
#pragma unroll
    for (int kc = 0; kc < 4; kc++) F3[kc] = ldw3(Wi0, I_, cb, kc, lane);
#pragma unroll
    for (int kc = 0; kc < 4; kc++) F3[4 + kc] = ldw3(Wh0, H_, cb, kc, lane);
#pragma unroll
    for (int kc = 0; kc < 8; kc++) G3[kc] = ldw3(Wi1, H_, cb, kc, lane);
    G3[8] = ldw3(Wn1, H_, cb, 0, lane); G3[9] = ldw3(Wn1, H_, cb, 1, lane);
  } else if (w == 1) {
#pragma unroll
    for (int kc = 0; kc < 4; kc++) F3[kc] = ldw3(Wh0, H_, cb, 4 + kc, lane);
#pragma unroll
    for (int kc = 0; kc < 4; kc++) F3[4 + kc] = ldw3(Wn0, I_, cb, kc, lane);
#pragma unroll
    for (int kc = 0; kc < 8; kc++) G3[kc] = ldw3(Wh1, H_, cb, kc, lane);
    G3[8] = ldw3(Wn1, H_, cb, 2, lane); G3[9] = ldw3(Wn1, H_, cb, 3, lane);
  } else if (w == 2) {
#pragma unroll
    for (int kc = 0; kc < 4; kc++) F3[kc] = ldw3(Wi0, I_, 256 + cb, kc, lane);
#pragma unroll
    for (int kc = 0; kc < 4; kc++) F3[4 + kc] = ldw3(Wh0, H_, 256 + cb, kc, lane);
#pragma unroll
    for (int kc = 0; kc < 8; kc++) G3[kc] = ldw3(Wi1, H_, 256 + cb, kc, lane);
    G3[8] = ldw3(Wn1, H_, cb, 4, lane); G3[9] = ldw3(Wn1, H_, cb, 5, lane);
  } else {
#pragma unroll
    for (int kc = 0; kc < 4; kc++) F3[kc] = ldw3(Wh0, H_, 256 + cb, 4 + kc, lane);
    // F3[4..7] unused for w3
#pragma unroll
    for (int kc = 0; kc < 8; kc++) G3[kc] = ldw3(Wh1, H_, 256 + cb, kc, lane);
    G3[8] = ldw3(Wn1, H_, cb, 6, lane); G3[9] = ldw3(Wn1, H_, cb, 7, lane);
  }

  __syncthreads();
  const int fast = s_fast;   // uniform per group; 1 => all sharers on one XCD's L2

  int aborted = 0;
  const f32x4 zz = {0.f, 0.f, 0.f, 0.f};

  for (int t = 0; t < T_; t++) {
    //===================== layer 0 =====================
    const float* xt = x + ((size_t)t * B_ + gb) * I_;
    f32x4 g0 = zz, g1 = zz, n0 = zz, n1 = zz;
    // x-dependent MFMAs first: independent of peers, overlaps the flag wait
    if (w == 0 || w == 2) {
#pragma unroll
      for (int kc = 0; kc < 4; kc++) {
        frag3 a = lda_x3(xt, I_, kc, lane);
        if (kc & 1) g1 = macc(a, F3[kc], g1); else g0 = macc(a, F3[kc], g0);
      }
    } else if (w == 1) {
#pragma unroll
      for (int kc = 0; kc < 4; kc++) {
        frag3 a = lda_x3(xt, I_, kc, lane);
        if (kc & 1) n1 = macc(a, F3[4 + kc], n1); else n0 = macc(a, F3[4 + kc], n0);
      }
    }
    if (tid == 0) {
      aborted = spinwait(f0, NC_ * t, aborted);        // h0[t-1] slices ready
      aborted = spinwait(f1, NC_ * t - NC_, aborted);  // h0 buffer WAR: L1[t-2] readers done
      if (!fast) __threadfence();                      // cross-XCD only: invalidate L1+L2
    }
    __syncthreads();
    {
      const ushort_t* P = h0sh + (size_t)((t + 1) & 1) * 3 * PL_;
      frag3 A[4];
      if (w == 0 || w == 2) {
#pragma unroll
        for (int kc = 0; kc < 4; kc++) A[kc] = lda_h3(P, gb, kc, lane);
        WAITVM();
#pragma unroll
        for (int kc = 0; kc < 4; kc++) {
          if (kc & 1) g1 = macc(A[kc], F3[4 + kc], g1); else g0 = macc(A[kc], F3[4 + kc], g0);
        }
      } else {
#pragma unroll
        for (int kc = 0; kc < 4; kc++) A[kc] = lda_h3(P, gb, 4 + kc, lane);
        WAITVM();
#pragma unroll
        for (int kc = 0; kc < 4; kc++) {
          if (kc & 1) g1 = macc(A[kc], F3[kc], g1); else g0 = macc(A[kc], F3[kc], g0);
        }
      }
    }
    store_d(&sP[w][0][0], g0 + g1, lane);
    if (w == 1) store_d(&sP[4][0][0], n0 + n1, lane);
    __syncthreads();
    {
      float gr = sP[0][pm][pc] + sP[1][pm][pc];
      float gz = sP[2][pm][pc] + sP[3][pm][pc];
      float np = sP[4][pm][pc];
      float h = h0own[tid];
      float r = 1.0f / (1.0f + expf(-gr));
      float z = 1.0f / (1.0f + expf(-gz));
      float n = tanhf(np + r * h);
      float hn = (1.0f - z) * n + z * h;
      h0own[tid] = hn;
    }
    __syncthreads();
    // publish h0[t]: 3 bf16 planes, plain packed-u32 stores (write-through to XCD L2)
    if (tid < 128) {
      int row = tid >> 3, cp = tid & 7;
      float v0 = h0own[row * 16 + cp * 2], v1 = h0own[row * 16 + cp * 2 + 1];
      ushort_t a0 = f2bf(v0); float r0 = v0 - bf2f(a0);
      ushort_t b0 = f2bf(r0); r0 -= bf2f(b0);
      ushort_t c0 = f2bf(r0);
      ushort_t a1 = f2bf(v1); float r1 = v1 - bf2f(a1);
      ushort_t b1 = f2bf(r1); r1 -= bf2f(b1);
      ushort_t c1 = f2bf(r1);
      size_t idx = (((size_t)(gb + row) * H_ + cb) >> 1) + cp;
      unsigned int* base = (unsigned int*)(h0sh + (size_t)(t & 1) * 3 * PL_);
      base[idx] = (unsigned)a0 | ((unsigned)a1 << 16);
      base[(PL_ >> 1) + idx] = (unsigned)b0 | ((unsigned)b1 << 16);
      base[PL_ + idx] = (unsigned)c0 | ((unsigned)c1 << 16);
    }
    __syncthreads();  // vmcnt(0) drained before barrier -> stores are in local L2
    if (tid == 0) {
      if (!fast) __threadfence();  // cross-XCD only: write-back local L2
      __hip_atomic_fetch_add(f0, 1, __ATOMIC_RELAXED, __HIP_MEMORY_SCOPE_AGENT);
    }

    //===================== layer 1 =====================
    if (tid == 0) {
      aborted = spinwait(f0, NC_ * (t + 1), aborted);  // h0[t] ready
      aborted = spinwait(f1, NC_ * t, aborted);        // h1[t-1] ready + WAR
      if (!fast) __threadfence();
    }
    __syncthreads();
    f32x4 a0v = zz, a1v = zz, nn = zz;
    {
      const ushort_t* Qb = h0sh + (size_t)(t & 1) * 3 * PL_;        // h0[t]
      const ushort_t* Rb = h1sh + (size_t)((t + 1) & 1) * 3 * PL_;  // h1[t-1]
      if (w == 0 || w == 2) {
        const int nb = (w == 0) ? 0 : 4;
        frag3 A[8];
#pragma unroll
        for (int kc = 0; kc < 8; kc++) A[kc] = lda_h3(Qb, gb, kc, lane);
        WAITVM();
#pragma unroll
        for (int kc = 0; kc < 8; kc++) {
          if (kc & 1) a1v = macc(A[kc], G3[kc], a1v); else a0v = macc(A[kc], G3[kc], a0v);
          if (kc == nb)     nn = macc(A[kc], G3[8], nn);
          if (kc == nb + 1) nn = macc(A[kc], G3[9], nn);
        }
      } else {
        const int nb = (w == 1) ? 2 : 6;
        frag3 A[8], Q0, Q1;
#pragma unroll
        for (int kc = 0; kc < 8; kc++) A[kc] = lda_h3(Rb, gb, kc, lane);
        Q0 = lda_h3(Qb, gb, nb, lane);
        Q1 = lda_h3(Qb, gb, nb + 1, lane);
        WAITVM();
#pragma unroll
        for (int kc = 0; kc < 8; kc++) {
          if (kc & 1) a1v = macc(A[kc], G3[kc], a1v); else a0v = macc(A[kc], G3[kc], a0v);
        }
        nn = macc(Q0, G3[8], nn);
        nn = macc(Q1, G3[9], nn);
      }
    }
    store_d(&sP[w][0][0], a0v + a1v, lane);
    store_d(&sP[4 + w][0][0], nn, lane);
    __syncthreads();
    {
      float gr = sP[0][pm][pc] + sP[1][pm][pc];
      float gz = sP[2][pm][pc] + sP[3][pm][pc];
      float np = sP[4][pm][pc] + sP[5][pm][pc] + sP[6][pm][pc] + sP[7][pm][pc];
      float h = h1own[tid];
      float r = 1.0f / (1.0f + expf(-gr));
      float z = 1.0f / (1.0f + expf(-gz));
      float n = tanhf(np + r * h);
      float hn = (1.0f - z) * n + z * h;
      h1own[tid] = hn;
      out[((size_t)t * B_ + gb + pm) * H_ + cb + pc] = hn;
    }
    __syncthreads();
    // publish h1[t]
    if (tid < 128) {
      int row = tid >> 3, cp = tid & 7;
      float v0 = h1own[row * 16 + cp * 2], v1 = h1own[row * 16 + cp * 2 + 1];
      ushort_t a0 = f2bf(v0); float r0 = v0 - bf2f(a0);
      ushort_t b0 = f2bf(r0); r0 -= bf2f(b0);
      ushort_t c0 = f2bf(r0);
      ushort_t a1 = f2bf(v1); float r1 = v1 - bf2f(a1);
      ushort_t b1 = f2bf(r1); r1 -= bf2f(b1);
      ushort_t c1 = f2bf(r1);
      size_t idx = (((size_t)(gb + row) * H_ + cb) >> 1) + cp;
      unsigned int* base = (unsigned int*)(h1sh + (size_t)(t & 1) * 3 * PL_);
      base[idx] = (unsigned)a0 | ((unsigned)a1 << 16);
      base[(PL_ >> 1) + idx] = (unsigned)b0 | ((unsigned)b1 << 16);
      base[PL_ + idx] = (unsigned)c0 | ((unsigned)c1 << 16);
    }
    __syncthreads();
    if (tid == 0) {
      if (!fast) __threadfence();
      __hip_atomic_fetch_add(f1, 1, __ATOMIC_RELAXED, __HIP_MEMORY_SCOPE_AGENT);
    }
  }

  // final states: out tail = [h0_final, h1_final]
  out[(size_t)T_ * B_ * H_ + (size_t)(gb + pm) * H_ + cb + pc] = h0own[tid];
  out[(size_t)T_ * B_ * H_ + (size_t)B_ * H_ + (size_t)(gb + pm) * H_ + cb + pc] = h1own[tid];

  // diagnostic sentinel: 4096 => spin abort (deadlock signature)
  if (tid == 0 && aborted) out[(size_t)gb * H_ + cb] = 4096.0f;
}

extern "C" void kernel_launch(void* const* d_in, const int* in_sizes, int n_in,
                              void* d_out, int out_size, void* d_ws, size_t ws_size,
                              hipStream_t stream) {
  const float* x     = (const float*)d_in[0];
  const float* state = (const float*)d_in[1];
  const float* Wi0   = (const float*)d_in[2];
  const float* Wh0   = (const float*)d_in[3];
  const float* Wn0   = (const float*)d_in[4];
  const float* Wi1   = (const float*)d_in[5];
  const float* Wh1   = (const float*)d_in[6];
  const float* Wn1   = (const float*)d_in[7];
  float* out = (float*)d_out;
  ushort_t* ws = (ushort_t*)d_ws;
  int* flags = (int*)((char*)d_ws + (size_t)WS_USHORTS * 2);

  prep_kernel<<<dim3((131072 + N_FLAGS + 255) / 256), dim3(256), 0, stream>>>(state, ws, flags);

  gru_main<<<dim3(NB_ * NC_), dim3(256), 0, stream>>>(
      x, Wi0, Wh0, Wn0, Wi1, Wh1, Wn1, state, out, ws, flags);
}